// Round 5
// baseline (157.397 us; speedup 1.0000x reference)
//
#include <hip/hip_runtime.h>
#include <cstdint>
#include <cstddef>

#define PRE_NMS  300
#define POST_K   100
#define NBUCKET  4096
#define CAND_MAX 2048
#define NCHUNK   16
#define SUB      128          // per-chunk candidate capacity (expected ~26)
#define NWORDS   5            // ceil(300/64)
#define SUP_STRIDE 6          // padded row stride (u64)
#define NMS_T    0.3f
#define SCORE_T  0.05f
#define FAST_T   0.9875f      // static fast-path threshold; fallback if <300 pass

typedef unsigned long long u64;

// ---------------------------------------------------------------------------
// Kernel A: wide scan. LDS-local counting, private per-chunk output regions,
// plain-store count publish. NO global atomics. grid = B*NCHUNK x 256.
// ---------------------------------------------------------------------------
__global__ __launch_bounds__(256) void scan_kernel(
    const float* __restrict__ cls_prob,   // B,N,2
    u64* __restrict__ candG,              // B x NCHUNK x SUB
    int* __restrict__ cntG,               // B x NCHUNK
    int N)
{
    const int b     = blockIdx.x >> 4;
    const int chunk = blockIdx.x & (NCHUNK - 1);
    const int nq    = N / 2;              // one float4 = 2 proposals
    const int per   = (nq + NCHUNK - 1) / NCHUNK;
    const int base  = chunk * per;
    const int end   = min(base + per, nq);

    __shared__ int lcnt;
    __shared__ u64 lbuf[SUB];
    if (threadIdx.x == 0) lcnt = 0;
    __syncthreads();

    const float4* cp = (const float4*)(cls_prob + (size_t)b * N * 2);
    for (int q = base + threadIdx.x; q < end; q += 256) {
        float4 v = cp[q];
        #pragma unroll
        for (int h = 0; h < 2; ++h) {
            float s = h ? v.w : v.y;
            if (s >= FAST_T) {
                int pos = atomicAdd(&lcnt, 1);          // LDS atomic: cheap
                if (pos < SUB) {
                    unsigned int m = __float_as_uint(s) ^ 0xFFFFFFFFu;
                    lbuf[pos] = ((u64)m << 32) | (unsigned int)(2 * q + h);
                }
            }
        }
    }
    __syncthreads();

    const int cnt = lcnt;
    u64* cb = candG + ((size_t)b * NCHUNK + chunk) * SUB;
    for (int i = threadIdx.x; i < min(cnt, SUB); i += 256) cb[i] = lbuf[i];
    if (threadIdx.x == 0) cntG[b * NCHUNK + chunk] = cnt;  // raw (may exceed SUB)
}

// ---------------------------------------------------------------------------
// Kernel B: per-batch sort + decode + NMS + output. grid = B x 512 threads.
// ---------------------------------------------------------------------------
__device__ __forceinline__ u64 keep_init_word(int Kv, int w) {
    int rem = Kv - 64 * w;
    if (rem >= 64) return ~0ull;
    if (rem <= 0)  return 0ull;
    return (1ull << rem) - 1ull;
}

__global__ __launch_bounds__(512) void proposal_kernel(
    const float* __restrict__ cls_prob,   // B,N,2
    const float* __restrict__ boxes,      // B,N,4
    const float* __restrict__ deltas,     // B,N,4
    const float* __restrict__ im_info,    // B,3
    float* __restrict__ out,              // B,POST_K,5
    const u64* __restrict__ candG,        // B x NCHUNK x SUB
    const int* __restrict__ cntG,         // B x NCHUNK
    int useWS, int N)
{
    const int b   = blockIdx.x;
    const int tid = threadIdx.x;
    const int NT  = 512;

    __shared__ u64 cand[CAND_MAX];                 // 16 KB (aliased as hist)
    int* hist = (int*)cand;                        // NBUCKET ints == 16 KB
    __shared__ float bx1[PRE_NMS], by1[PRE_NMS], bx2[PRE_NMS], by2[PRE_NMS], barea[PRE_NMS];
    __shared__ u64 supRow[PRE_NMS * SUP_STRIDE];   // 14.4 KB, row-major padded
    __shared__ u64 keepw[NWORDS];
    __shared__ int sel[POST_K];
    __shared__ int n_out;
    __shared__ int sh_cc;
    __shared__ int sh_ok;
    __shared__ int cand_count;
    __shared__ int cutoff;
    __shared__ int ccnt[NCHUNK], coff[NCHUNK + 1];

    if (tid == 0) cand_count = 0;
    __syncthreads();

    const float4* cp = (const float4*)(cls_prob + (size_t)b * N * 2);
    const int nq = N / 2;

    // ---- 1. get candidates: fast path gathers per-chunk lists from ws ----
    if (useWS && tid < NCHUNK) ccnt[tid] = cntG[b * NCHUNK + tid];
    __syncthreads();
    if (tid == 0) {
        int ok = useWS;
        int tot = 0;
        if (useWS) {
            for (int c = 0; c < NCHUNK; ++c) {
                if (ccnt[c] > SUB) ok = 0;
                coff[c] = tot;
                tot += ccnt[c];
            }
            coff[NCHUNK] = tot;
            if (tot < PRE_NMS || tot > CAND_MAX) ok = 0;
        }
        sh_ok = ok;
        sh_cc = tot;
    }
    __syncthreads();
    const bool fast = (sh_ok != 0);
    int cc;

    if (fast) {
        cc = sh_cc;
        const int c = tid >> 5;                     // 16 chunks x 32 threads
        const u64* cb = candG + ((size_t)b * NCHUNK + c) * SUB;
        const int n = ccnt[c], o = coff[c];
        for (int i = tid & 31; i < n; i += 32) cand[o + i] = cb[i];
    } else {
        // full scan fallback (data-dependent; covers ws-overflow / no-ws)
        for (int q = tid; q < nq; q += NT) {
            float4 v = cp[q];
            #pragma unroll
            for (int h = 0; h < 2; ++h) {
                float s = h ? v.w : v.y;
                if (s >= FAST_T) {
                    int pos = atomicAdd(&cand_count, 1);
                    if (pos < CAND_MAX) {
                        unsigned int m = __float_as_uint(s) ^ 0xFFFFFFFFu;
                        cand[pos] = ((u64)m << 32) | (unsigned int)(2 * q + h);
                    }
                }
            }
        }
        __syncthreads();
        if (cand_count < PRE_NMS) {
            // histogram fallback (hist aliases cand; cand dead here)
            for (int i = tid; i < NBUCKET; i += NT) hist[i] = 0;
            __syncthreads();
            for (int q = tid; q < nq; q += NT) {
                float4 v = cp[q];
                if (v.y >= SCORE_T) atomicAdd(&hist[min((int)(v.y * (float)NBUCKET), NBUCKET - 1)], 1);
                if (v.w >= SCORE_T) atomicAdd(&hist[min((int)(v.w * (float)NBUCKET), NBUCKET - 1)], 1);
            }
            __syncthreads();
            if (tid == 0) {
                int acc = 0, c = 0;
                for (int i = NBUCKET - 1; i >= 0; --i) {
                    acc += hist[i];
                    if (acc >= PRE_NMS) { c = i; break; }
                }
                cutoff = c;
                cand_count = 0;
            }
            __syncthreads();
            const int c = cutoff;
            for (int q = tid; q < nq; q += NT) {
                float4 v = cp[q];
                #pragma unroll
                for (int h = 0; h < 2; ++h) {
                    float s = h ? v.w : v.y;
                    if (s >= SCORE_T) {
                        int bu = min((int)(s * (float)NBUCKET), NBUCKET - 1);
                        if (bu >= c) {
                            int pos = atomicAdd(&cand_count, 1);
                            if (pos < CAND_MAX) {
                                unsigned int m = __float_as_uint(s) ^ 0xFFFFFFFFu;
                                cand[pos] = ((u64)m << 32) | (unsigned int)(2 * q + h);
                            }
                        }
                    }
                }
            }
            __syncthreads();
        }
        cc = min(cand_count, CAND_MAX);
        if (tid == 0) sh_cc = cc;
        __syncthreads();
        cc = sh_cc;
    }
    __syncthreads();

    // ---- 2. sort ascending: key = (~score_bits, idx) ----
    if (cc <= 512) {
        // hybrid bitonic: one key per thread, shfl for j<64, LDS for j>=64
        if (tid >= cc) cand[tid] = ~0ull;
        __syncthreads();
        u64 key = cand[tid];
        #pragma unroll
        for (int k = 2; k <= 64; k <<= 1) {
            bool up = ((tid & k) == 0);
            for (int j = k >> 1; j > 0; j >>= 1) {
                u64 other = __shfl_xor(key, j, 64);
                bool take_min = (((tid & j) == 0) == up);
                bool le = (key <= other);
                key = (take_min == le) ? key : other;
            }
        }
        #pragma unroll
        for (int k = 128; k <= 512; k <<= 1) {
            bool up = ((tid & k) == 0);
            for (int j = k >> 1; j >= 64; j >>= 1) {
                cand[tid] = key;
                __syncthreads();
                u64 other = cand[tid ^ j];
                __syncthreads();
                bool take_min = (((tid & j) == 0) == up);
                bool le = (key <= other);
                key = (take_min == le) ? key : other;
            }
            for (int j = 32; j > 0; j >>= 1) {
                u64 other = __shfl_xor(key, j, 64);
                bool take_min = (((tid & j) == 0) == up);
                bool le = (key <= other);
                key = (take_min == le) ? key : other;
            }
        }
        cand[tid] = key;
        __syncthreads();
    } else {
        // generic LDS bitonic for S in {1024, 2048}
        int S = (cc <= 1024) ? 1024 : 2048;
        for (int i = cc + tid; i < S; i += NT) cand[i] = ~0ull;
        __syncthreads();
        for (int k = 2; k <= S; k <<= 1) {
            for (int j = k >> 1; j > 0; j >>= 1) {
                for (int i = tid; i < S; i += NT) {
                    int l = i ^ j;
                    if (l > i) {
                        u64 a = cand[i], d = cand[l];
                        bool up = ((i & k) == 0);
                        if ((a > d) == up) { cand[i] = d; cand[l] = a; }
                    }
                }
                __syncthreads();
            }
        }
    }

    const int Kv = min(cc, PRE_NMS);

    // ---- 3. decode + clip top-300 ----
    const float hmax = im_info[b * 3 + 0] - 1.0f;
    const float wmax = im_info[b * 3 + 1] - 1.0f;
    if (tid < PRE_NMS) {
        int k = tid;
        int idx = (k < Kv) ? (int)(cand[k] & 0xFFFFFFFFull) : 0;
        float4 bo = *(const float4*)(boxes  + ((size_t)b * N + idx) * 4);
        float4 de = *(const float4*)(deltas + ((size_t)b * N + idx) * 4);
        float w  = bo.z - bo.x + 1.0f;
        float hh = bo.w - bo.y + 1.0f;
        float cx = bo.x + 0.5f * w;
        float cy = bo.y + 0.5f * hh;
        float dx = de.x * 0.1f, dy = de.y * 0.1f;
        float dw = de.z * 0.2f, dh = de.w * 0.2f;
        float pcx = dx * w + cx;
        float pcy = dy * hh + cy;
        float pw  = expf(dw) * w;
        float ph  = expf(dh) * hh;
        float x1 = pcx - 0.5f * pw, y1 = pcy - 0.5f * ph;
        float x2 = pcx + 0.5f * pw, y2 = pcy + 0.5f * ph;
        x1 = fminf(fmaxf(x1, 0.0f), wmax);
        y1 = fminf(fmaxf(y1, 0.0f), hmax);
        x2 = fminf(fmaxf(x2, 0.0f), wmax);
        y2 = fminf(fmaxf(y2, 0.0f), hmax);
        bx1[k] = x1; by1[k] = y1; bx2[k] = x2; by2[k] = y2;
        barea[k] = (x2 - x1 + 1.0f) * (y2 - y1 + 1.0f);
    }
    __syncthreads();

    // ---- 4. suppression matrix, row-major; only j>i bits are ever read ----
    for (int t = tid; t < PRE_NMS * NWORDS; t += NT) {
        int w = t / PRE_NMS;
        int i = t - w * PRE_NMS;
        int jbase = w * 64;
        int jend  = min(jbase + 64, PRE_NMS);
        if (jend <= i + 1) continue;      // whole word <= i: bits never read
        float xi1 = bx1[i], yi1 = by1[i], xi2 = bx2[i], yi2 = by2[i], ai = barea[i];
        u64 bits = 0;
        int jstart = max(jbase, i + 1);   // bits j<=i never read
        for (int j = jstart; j < jend; ++j) {
            float xx1 = fmaxf(xi1, bx1[j]);
            float yy1 = fmaxf(yi1, by1[j]);
            float xx2 = fminf(xi2, bx2[j]);
            float yy2 = fminf(yi2, by2[j]);
            float iw = fmaxf(xx2 - xx1 + 1.0f, 0.0f);
            float ih = fmaxf(yy2 - yy1 + 1.0f, 0.0f);
            float inter = iw * ih;
            float iou = inter / (ai + barea[j] - inter);
            if (iou > NMS_T) bits |= (1ull << (j - jbase));
        }
        supRow[i * SUP_STRIDE + w] = bits;
    }
    __syncthreads();

    // ---- 5. greedy NMS: wave 0, keep + 3-deep row pipeline in NAMED scalar
    //      registers (no arrays -> no scratch spill; R4's pb[8][5] spilled) ----
    if (tid < 64) {
        u64 kw0 = keep_init_word(Kv, 0);
        u64 kw1 = keep_init_word(Kv, 1);
        u64 kw2 = keep_init_word(Kv, 2);
        u64 kw3 = keep_init_word(Kv, 3);
        u64 kw4 = keep_init_word(Kv, 4);

        const u64* r;
        r = supRow;                     u64 c0=r[0], c1=r[1], c2=r[2], c3=r[3], c4=r[4];
        r = supRow + SUP_STRIDE;        u64 p0=r[0], p1=r[1], p2=r[2], p3=r[3], p4=r[4];
        r = supRow + 2 * SUP_STRIDE;    u64 q0=r[0], q1=r[1], q2=r[2], q3=r[3], q4=r[4];

        int nk = 0;
        for (int i = 0; i < PRE_NMS; ++i) {
            int wi = i >> 6, bi = i & 63;
            u64 cw = (wi == 0) ? kw0 : (wi == 1) ? kw1 : (wi == 2) ? kw2 : (wi == 3) ? kw3 : kw4;
            if ((cw >> bi) & 1ull) {
                u64 upper = (bi == 63) ? 0ull : (~0ull << (bi + 1));
                u64 m0 = (wi == 0) ? (c0 & upper) : 0ull;
                u64 m1 = (wi < 1) ? c1 : ((wi == 1) ? (c1 & upper) : 0ull);
                u64 m2 = (wi < 2) ? c2 : ((wi == 2) ? (c2 & upper) : 0ull);
                u64 m3 = (wi < 3) ? c3 : ((wi == 3) ? (c3 & upper) : 0ull);
                u64 m4 = (wi < 4) ? c4 : (c4 & upper);
                kw0 &= ~m0; kw1 &= ~m1; kw2 &= ~m2; kw3 &= ~m3; kw4 &= ~m4;
                if (++nk >= POST_K) break;
            }
            c0 = p0; c1 = p1; c2 = p2; c3 = p3; c4 = p4;
            p0 = q0; p1 = q1; p2 = q2; p3 = q3; p4 = q4;
            int nx = i + 3;
            if (nx < PRE_NMS) {
                r = supRow + nx * SUP_STRIDE;
                q0 = r[0]; q1 = r[1]; q2 = r[2]; q3 = r[3]; q4 = r[4];
            }
        }
        if (tid == 0) {
            keepw[0] = kw0; keepw[1] = kw1; keepw[2] = kw2; keepw[3] = kw3; keepw[4] = kw4;
            n_out = nk;
        }
    }
    __syncthreads();

    // ---- 6. parallel compaction ----
    if (tid < PRE_NMS) {
        int wi = tid >> 6, bi = tid & 63;
        u64 w = keepw[wi];
        int prefix = 0;
        #pragma unroll
        for (int ww = 0; ww < NWORDS; ++ww)
            if (ww < wi) prefix += __popcll(keepw[ww]);
        prefix += __popcll(w & ((1ull << bi) - 1ull));
        if (((w >> bi) & 1ull) && prefix < POST_K) sel[prefix] = tid;
    }
    __syncthreads();

    // ---- 7. output ----
    if (tid < POST_K) {
        float* op = out + ((size_t)b * POST_K + tid) * 5;
        op[0] = (float)b;
        if (tid < n_out) {
            int k = sel[tid];
            op[1] = bx1[k]; op[2] = by1[k]; op[3] = bx2[k]; op[4] = by2[k];
        } else {
            op[1] = 0.0f; op[2] = 0.0f; op[3] = 0.0f; op[4] = 0.0f;
        }
    }
}

extern "C" void kernel_launch(void* const* d_in, const int* in_sizes, int n_in,
                              void* d_out, int out_size, void* d_ws, size_t ws_size,
                              hipStream_t stream) {
    const float* cls_prob = (const float*)d_in[0];
    const float* boxes    = (const float*)d_in[1];
    const float* deltas   = (const float*)d_in[2];
    const float* im_info  = (const float*)d_in[3];
    float* out = (float*)d_out;

    const int B = in_sizes[3] / 3;
    const int N = in_sizes[0] / (B * 2);

    int* cntG   = (int*)d_ws;                               // B*NCHUNK ints
    u64* candG  = (u64*)((char*)d_ws + 16384);              // B*NCHUNK*SUB u64
    size_t need = 16384 + (size_t)B * NCHUNK * SUB * sizeof(u64);
    int useWS   = (ws_size >= need && B * NCHUNK * (int)sizeof(int) <= 16384) ? 1 : 0;

    if (useWS) {
        scan_kernel<<<B * NCHUNK, 256, 0, stream>>>(cls_prob, candG, cntG, N);
    }
    proposal_kernel<<<B, 512, 0, stream>>>(cls_prob, boxes, deltas, im_info, out,
                                           candG, cntG, useWS, N);
}

// Round 6
// 142.436 us; speedup vs baseline: 1.1050x; 1.1050x over previous
//
#include <hip/hip_runtime.h>
#include <cstdint>
#include <cstddef>

#define PRE_NMS  300
#define POST_K   100
#define NBUCKET  4096
#define CAND_MAX 2048
#define NCHUNK   16
#define SUB      128          // per-chunk candidate capacity (expected ~26)
#define NWORDS   5            // ceil(300/64)
#define SUP_STRIDE 6          // padded row stride (u64)
#define NMS_T    0.3f
#define SCORE_T  0.05f
#define FAST_T   0.9875f      // static fast-path threshold; fallback if <300 pass

typedef unsigned long long u64;

// ---------------------------------------------------------------------------
// Kernel A: wide scan. LDS-local counting, private per-chunk output regions,
// plain-store count publish. NO global atomics. grid = B*NCHUNK x 256.
// ---------------------------------------------------------------------------
__global__ __launch_bounds__(256) void scan_kernel(
    const float* __restrict__ cls_prob,   // B,N,2
    u64* __restrict__ candG,              // B x NCHUNK x SUB
    int* __restrict__ cntG,               // B x NCHUNK
    int N)
{
    const int b     = blockIdx.x >> 4;
    const int chunk = blockIdx.x & (NCHUNK - 1);
    const int nq    = N / 2;              // one float4 = 2 proposals
    const int per   = (nq + NCHUNK - 1) / NCHUNK;
    const int base  = chunk * per;
    const int end   = min(base + per, nq);

    __shared__ int lcnt;
    __shared__ u64 lbuf[SUB];
    if (threadIdx.x == 0) lcnt = 0;
    __syncthreads();

    const float4* cp = (const float4*)(cls_prob + (size_t)b * N * 2);
    for (int q = base + threadIdx.x; q < end; q += 256) {
        float4 v = cp[q];
        #pragma unroll
        for (int h = 0; h < 2; ++h) {
            float s = h ? v.w : v.y;
            if (s >= FAST_T) {
                int pos = atomicAdd(&lcnt, 1);          // LDS atomic: cheap
                if (pos < SUB) {
                    unsigned int m = __float_as_uint(s) ^ 0xFFFFFFFFu;
                    lbuf[pos] = ((u64)m << 32) | (unsigned int)(2 * q + h);
                }
            }
        }
    }
    __syncthreads();

    const int cnt = lcnt;
    u64* cb = candG + ((size_t)b * NCHUNK + chunk) * SUB;
    for (int i = threadIdx.x; i < min(cnt, SUB); i += 256) cb[i] = lbuf[i];
    if (threadIdx.x == 0) cntG[b * NCHUNK + chunk] = cnt;  // raw (may exceed SUB)
}

// ---------------------------------------------------------------------------
// Kernel B: per-batch rank-select + decode + NMS + output. grid = B x 512.
// ---------------------------------------------------------------------------
__device__ __forceinline__ u64 keep_init_word(int Kv, int w) {
    int rem = Kv - 64 * w;
    if (rem >= 64) return ~0ull;
    if (rem <= 0)  return 0ull;
    return (1ull << rem) - 1ull;
}

__global__ __launch_bounds__(512) void proposal_kernel(
    const float* __restrict__ cls_prob,   // B,N,2
    const float* __restrict__ boxes,      // B,N,4
    const float* __restrict__ deltas,     // B,N,4
    const float* __restrict__ im_info,    // B,3
    float* __restrict__ out,              // B,POST_K,5
    const u64* __restrict__ candG,        // B x NCHUNK x SUB
    const int* __restrict__ cntG,         // B x NCHUNK
    int useWS, int N)
{
    const int b   = blockIdx.x;
    const int tid = threadIdx.x;
    const int NT  = 512;

    __shared__ u64 cand[CAND_MAX];                 // 16 KB (aliased as hist)
    int* hist = (int*)cand;                        // NBUCKET ints == 16 KB
    __shared__ u64 skey[PRE_NMS];                  // rank-selected top-300 keys
    __shared__ float bx1[PRE_NMS], by1[PRE_NMS], bx2[PRE_NMS], by2[PRE_NMS], barea[PRE_NMS];
    __shared__ u64 supRow[PRE_NMS * SUP_STRIDE];   // 14.4 KB, row-major padded
    __shared__ u64 keepw[NWORDS];
    __shared__ int sel[POST_K];
    __shared__ int n_out;
    __shared__ int sh_cc;
    __shared__ int sh_ok;
    __shared__ int cand_count;
    __shared__ int cutoff;
    __shared__ int ccnt[NCHUNK], coff[NCHUNK + 1];

    if (tid == 0) cand_count = 0;
    __syncthreads();

    const float4* cp = (const float4*)(cls_prob + (size_t)b * N * 2);
    const int nq = N / 2;

    // ---- 1. get candidates: fast path gathers per-chunk lists from ws ----
    if (useWS && tid < NCHUNK) ccnt[tid] = cntG[b * NCHUNK + tid];
    __syncthreads();
    if (tid == 0) {
        int ok = useWS;
        int tot = 0;
        if (useWS) {
            for (int c = 0; c < NCHUNK; ++c) {
                if (ccnt[c] > SUB) ok = 0;
                coff[c] = tot;
                tot += ccnt[c];
            }
            coff[NCHUNK] = tot;
            if (tot < PRE_NMS || tot > CAND_MAX) ok = 0;
        }
        sh_ok = ok;
        sh_cc = tot;
    }
    __syncthreads();
    const bool fast = (sh_ok != 0);
    int cc;

    if (fast) {
        cc = sh_cc;
        const int c = tid >> 5;                     // 16 chunks x 32 threads
        const u64* cb = candG + ((size_t)b * NCHUNK + c) * SUB;
        const int n = ccnt[c], o = coff[c];
        for (int i = tid & 31; i < n; i += 32) cand[o + i] = cb[i];
    } else {
        // full scan fallback (data-dependent; covers ws-overflow / no-ws)
        for (int q = tid; q < nq; q += NT) {
            float4 v = cp[q];
            #pragma unroll
            for (int h = 0; h < 2; ++h) {
                float s = h ? v.w : v.y;
                if (s >= FAST_T) {
                    int pos = atomicAdd(&cand_count, 1);
                    if (pos < CAND_MAX) {
                        unsigned int m = __float_as_uint(s) ^ 0xFFFFFFFFu;
                        cand[pos] = ((u64)m << 32) | (unsigned int)(2 * q + h);
                    }
                }
            }
        }
        __syncthreads();
        if (cand_count < PRE_NMS) {
            // histogram fallback (hist aliases cand; cand dead here)
            for (int i = tid; i < NBUCKET; i += NT) hist[i] = 0;
            __syncthreads();
            for (int q = tid; q < nq; q += NT) {
                float4 v = cp[q];
                if (v.y >= SCORE_T) atomicAdd(&hist[min((int)(v.y * (float)NBUCKET), NBUCKET - 1)], 1);
                if (v.w >= SCORE_T) atomicAdd(&hist[min((int)(v.w * (float)NBUCKET), NBUCKET - 1)], 1);
            }
            __syncthreads();
            if (tid == 0) {
                int acc = 0, c = 0;
                for (int i = NBUCKET - 1; i >= 0; --i) {
                    acc += hist[i];
                    if (acc >= PRE_NMS) { c = i; break; }
                }
                cutoff = c;
                cand_count = 0;
            }
            __syncthreads();
            const int c = cutoff;
            for (int q = tid; q < nq; q += NT) {
                float4 v = cp[q];
                #pragma unroll
                for (int h = 0; h < 2; ++h) {
                    float s = h ? v.w : v.y;
                    if (s >= SCORE_T) {
                        int bu = min((int)(s * (float)NBUCKET), NBUCKET - 1);
                        if (bu >= c) {
                            int pos = atomicAdd(&cand_count, 1);
                            if (pos < CAND_MAX) {
                                unsigned int m = __float_as_uint(s) ^ 0xFFFFFFFFu;
                                cand[pos] = ((u64)m << 32) | (unsigned int)(2 * q + h);
                            }
                        }
                    }
                }
            }
            __syncthreads();
        }
        cc = min(cand_count, CAND_MAX);
        if (tid == 0) sh_cc = cc;
        __syncthreads();
        cc = sh_cc;
    }

    // ---- 2. rank-selection "sort": rank = #keys smaller; skey[rank] = key ----
    // Keys are unique (index embedded) so rank is an exact sort permutation.
    // Fully parallel, barrier-light; inner reads are wave-broadcast.
    for (int k = tid; k < PRE_NMS; k += NT) skey[k] = ~0ull;
    __syncthreads();
    for (int c = tid; c < cc; c += NT) {
        u64 my = cand[c];
        int rank = 0;
        for (int k = 0; k < cc; ++k) rank += (cand[k] < my) ? 1 : 0;
        if (rank < PRE_NMS) skey[rank] = my;
    }
    __syncthreads();

    const int Kv = min(cc, PRE_NMS);

    // ---- 3. decode + clip top-300 ----
    const float hmax = im_info[b * 3 + 0] - 1.0f;
    const float wmax = im_info[b * 3 + 1] - 1.0f;
    if (tid < PRE_NMS) {
        int k = tid;
        int idx = (k < Kv) ? (int)(skey[k] & 0xFFFFFFFFull) : 0;
        float4 bo = *(const float4*)(boxes  + ((size_t)b * N + idx) * 4);
        float4 de = *(const float4*)(deltas + ((size_t)b * N + idx) * 4);
        float w  = bo.z - bo.x + 1.0f;
        float hh = bo.w - bo.y + 1.0f;
        float cx = bo.x + 0.5f * w;
        float cy = bo.y + 0.5f * hh;
        float dx = de.x * 0.1f, dy = de.y * 0.1f;
        float dw = de.z * 0.2f, dh = de.w * 0.2f;
        float pcx = dx * w + cx;
        float pcy = dy * hh + cy;
        float pw  = expf(dw) * w;
        float ph  = expf(dh) * hh;
        float x1 = pcx - 0.5f * pw, y1 = pcy - 0.5f * ph;
        float x2 = pcx + 0.5f * pw, y2 = pcy + 0.5f * ph;
        x1 = fminf(fmaxf(x1, 0.0f), wmax);
        y1 = fminf(fmaxf(y1, 0.0f), hmax);
        x2 = fminf(fmaxf(x2, 0.0f), wmax);
        y2 = fminf(fmaxf(y2, 0.0f), hmax);
        bx1[k] = x1; by1[k] = y1; bx2[k] = x2; by2[k] = y2;
        barea[k] = (x2 - x1 + 1.0f) * (y2 - y1 + 1.0f);
    }
    __syncthreads();

    // ---- 4. suppression matrix, row-major; bits j<=i are written as 0 so
    //      NMS can AND rows unmasked ----
    for (int t = tid; t < PRE_NMS * NWORDS; t += NT) {
        int w = t / PRE_NMS;
        int i = t - w * PRE_NMS;
        int jbase = w * 64;
        int jend  = min(jbase + 64, PRE_NMS);
        u64 bits = 0;
        int jstart = max(jbase, i + 1);   // bits j<=i stay 0
        if (jstart < jend) {
            float xi1 = bx1[i], yi1 = by1[i], xi2 = bx2[i], yi2 = by2[i], ai = barea[i];
            for (int j = jstart; j < jend; ++j) {
                float xx1 = fmaxf(xi1, bx1[j]);
                float yy1 = fmaxf(yi1, by1[j]);
                float xx2 = fminf(xi2, bx2[j]);
                float yy2 = fminf(yi2, by2[j]);
                float iw = fmaxf(xx2 - xx1 + 1.0f, 0.0f);
                float ih = fmaxf(yy2 - yy1 + 1.0f, 0.0f);
                float inter = iw * ih;
                float iou = inter / (ai + barea[j] - inter);
                if (iou > NMS_T) bits |= (1ull << (j - jbase));
            }
        }
        supRow[i * SUP_STRIDE + w] = bits;
    }
    __syncthreads();

    // ---- 5. greedy NMS: wave 0 uniform, ffs-driven alive-skip.
    //      Only ~#kept (<=100 + word scans) dependent steps, not 300. ----
    if (tid < 64) {
        u64 kw0 = keep_init_word(Kv, 0);
        u64 kw1 = keep_init_word(Kv, 1);
        u64 kw2 = keep_init_word(Kv, 2);
        u64 kw3 = keep_init_word(Kv, 3);
        u64 kw4 = keep_init_word(Kv, 4);

        int nk = 0;
        #pragma unroll
        for (int wi = 0; wi < NWORDS; ++wi) {
            if (nk >= POST_K) break;
            u64 w = (wi == 0) ? kw0 : (wi == 1) ? kw1 : (wi == 2) ? kw2 : (wi == 3) ? kw3 : kw4;
            while (w != 0ull && nk < POST_K) {
                int bit = __ffsll(w) - 1;
                int i = wi * 64 + bit;
                const u64* r = supRow + i * SUP_STRIDE;
                u64 r0 = r[0], r1 = r[1], r2 = r[2], r3 = r[3], r4 = r[4];
                kw0 &= ~r0; kw1 &= ~r1; kw2 &= ~r2; kw3 &= ~r3; kw4 &= ~r4;
                ++nk;
                u64 self = (wi == 0) ? kw0 : (wi == 1) ? kw1 : (wi == 2) ? kw2 : (wi == 3) ? kw3 : kw4;
                u64 below = (bit == 63) ? ~0ull : ((1ull << (bit + 1)) - 1ull);
                w = self & ~below;        // alive bits strictly above current
            }
        }
        if (tid == 0) {
            keepw[0] = kw0; keepw[1] = kw1; keepw[2] = kw2; keepw[3] = kw3; keepw[4] = kw4;
            n_out = nk;
        }
    }
    __syncthreads();

    // ---- 6. parallel compaction ----
    // keepw still has alive bits beyond the 100th kept; cap via prefix<POST_K.
    if (tid < PRE_NMS) {
        int wi = tid >> 6, bi = tid & 63;
        u64 w = keepw[wi];
        int prefix = 0;
        #pragma unroll
        for (int ww = 0; ww < NWORDS; ++ww)
            if (ww < wi) prefix += __popcll(keepw[ww]);
        prefix += __popcll(w & ((1ull << bi) - 1ull));
        if (((w >> bi) & 1ull) && prefix < POST_K) sel[prefix] = tid;
    }
    __syncthreads();

    // ---- 7. output ----
    if (tid < POST_K) {
        float* op = out + ((size_t)b * POST_K + tid) * 5;
        op[0] = (float)b;
        if (tid < n_out) {
            int k = sel[tid];
            op[1] = bx1[k]; op[2] = by1[k]; op[3] = bx2[k]; op[4] = by2[k];
        } else {
            op[1] = 0.0f; op[2] = 0.0f; op[3] = 0.0f; op[4] = 0.0f;
        }
    }
}

extern "C" void kernel_launch(void* const* d_in, const int* in_sizes, int n_in,
                              void* d_out, int out_size, void* d_ws, size_t ws_size,
                              hipStream_t stream) {
    const float* cls_prob = (const float*)d_in[0];
    const float* boxes    = (const float*)d_in[1];
    const float* deltas   = (const float*)d_in[2];
    const float* im_info  = (const float*)d_in[3];
    float* out = (float*)d_out;

    const int B = in_sizes[3] / 3;
    const int N = in_sizes[0] / (B * 2);

    int* cntG   = (int*)d_ws;                               // B*NCHUNK ints
    u64* candG  = (u64*)((char*)d_ws + 16384);              // B*NCHUNK*SUB u64
    size_t need = 16384 + (size_t)B * NCHUNK * SUB * sizeof(u64);
    int useWS   = (ws_size >= need && B * NCHUNK * (int)sizeof(int) <= 16384) ? 1 : 0;

    if (useWS) {
        scan_kernel<<<B * NCHUNK, 256, 0, stream>>>(cls_prob, candG, cntG, N);
    }
    proposal_kernel<<<B, 512, 0, stream>>>(cls_prob, boxes, deltas, im_info, out,
                                           candG, cntG, useWS, N);
}

// Round 7
// 140.913 us; speedup vs baseline: 1.1170x; 1.0108x over previous
//
#include <hip/hip_runtime.h>
#include <cstdint>
#include <cstddef>

#define PRE_NMS  300
#define POST_K   100
#define NBUCKET  4096
#define CAND_MAX 2048
#define NCHUNK   16
#define SUB      128          // per-chunk candidate capacity (expected ~26)
#define NWORDS   5            // ceil(300/64)
#define SUP_STRIDE 8          // row stride (u64): 64B rows, 16B-aligned
#define NMS_T    0.3f
#define SCORE_T  0.05f
#define FAST_T   0.9875f      // static fast-path threshold; fallback if <300 pass

typedef unsigned long long u64;

// ---------------------------------------------------------------------------
// Kernel A: wide scan. LDS-local counting, private per-chunk output regions,
// plain-store count publish. NO global atomics. grid = B*NCHUNK x 256.
// ---------------------------------------------------------------------------
__global__ __launch_bounds__(256) void scan_kernel(
    const float* __restrict__ cls_prob,   // B,N,2
    u64* __restrict__ candG,              // B x NCHUNK x SUB
    int* __restrict__ cntG,               // B x NCHUNK
    int N)
{
    const int b     = blockIdx.x >> 4;
    const int chunk = blockIdx.x & (NCHUNK - 1);
    const int nq    = N / 2;              // one float4 = 2 proposals
    const int per   = (nq + NCHUNK - 1) / NCHUNK;
    const int base  = chunk * per;
    const int end   = min(base + per, nq);

    __shared__ int lcnt;
    __shared__ u64 lbuf[SUB];
    if (threadIdx.x == 0) lcnt = 0;
    __syncthreads();

    const float4* cp = (const float4*)(cls_prob + (size_t)b * N * 2);
    for (int q = base + threadIdx.x; q < end; q += 256) {
        float4 v = cp[q];
        #pragma unroll
        for (int h = 0; h < 2; ++h) {
            float s = h ? v.w : v.y;
            if (s >= FAST_T) {
                int pos = atomicAdd(&lcnt, 1);          // LDS atomic: cheap
                if (pos < SUB) {
                    unsigned int m = __float_as_uint(s) ^ 0xFFFFFFFFu;
                    lbuf[pos] = ((u64)m << 32) | (unsigned int)(2 * q + h);
                }
            }
        }
    }
    __syncthreads();

    const int cnt = lcnt;
    u64* cb = candG + ((size_t)b * NCHUNK + chunk) * SUB;
    for (int i = threadIdx.x; i < min(cnt, SUB); i += 256) cb[i] = lbuf[i];
    if (threadIdx.x == 0) cntG[b * NCHUNK + chunk] = cnt;  // raw (may exceed SUB)
}

// ---------------------------------------------------------------------------
// Kernel B: per-batch rank-select + decode + NMS + output. grid = B x 512.
// ---------------------------------------------------------------------------
__device__ __forceinline__ u64 keep_init_word(int Kv, int w) {
    int rem = Kv - 64 * w;
    if (rem >= 64) return ~0ull;
    if (rem <= 0)  return 0ull;
    return (1ull << rem) - 1ull;
}

__global__ __launch_bounds__(512) void proposal_kernel(
    const float* __restrict__ cls_prob,   // B,N,2
    const float* __restrict__ boxes,      // B,N,4
    const float* __restrict__ deltas,     // B,N,4
    const float* __restrict__ im_info,    // B,3
    float* __restrict__ out,              // B,POST_K,5
    const u64* __restrict__ candG,        // B x NCHUNK x SUB
    const int* __restrict__ cntG,         // B x NCHUNK
    int useWS, int N)
{
    const int b   = blockIdx.x;
    const int tid = threadIdx.x;
    const int NT  = 512;

    __shared__ u64 cand[CAND_MAX];                 // 16 KB (aliased as hist)
    int* hist = (int*)cand;                        // NBUCKET ints == 16 KB
    __shared__ float4 bb[PRE_NMS];                 // decoded boxes at sorted rank
    __shared__ u64 supRow[PRE_NMS * SUP_STRIDE];   // 19.2 KB, 64B-aligned rows
    __shared__ u64 keepw[NWORDS];
    __shared__ int sel[POST_K];
    __shared__ int n_out;
    __shared__ int sh_cc;
    __shared__ int sh_ok;
    __shared__ int cand_count;
    __shared__ int cutoff;
    __shared__ int ccnt[NCHUNK], coff[NCHUNK + 1];

    if (tid == 0) cand_count = 0;
    __syncthreads();

    const float4* cp = (const float4*)(cls_prob + (size_t)b * N * 2);
    const int nq = N / 2;

    // ---- 1. get candidates: fast path gathers per-chunk lists from ws ----
    if (useWS && tid < NCHUNK) ccnt[tid] = cntG[b * NCHUNK + tid];
    __syncthreads();
    if (tid == 0) {
        int ok = useWS;
        int tot = 0;
        if (useWS) {
            for (int c = 0; c < NCHUNK; ++c) {
                if (ccnt[c] > SUB) ok = 0;
                coff[c] = tot;
                tot += ccnt[c];
            }
            coff[NCHUNK] = tot;
            if (tot < PRE_NMS || tot > CAND_MAX) ok = 0;
        }
        sh_ok = ok;
        sh_cc = tot;
    }
    __syncthreads();
    const bool fast = (sh_ok != 0);
    int cc;

    if (fast) {
        cc = sh_cc;
        const int c = tid >> 5;                     // 16 chunks x 32 threads
        const u64* cb = candG + ((size_t)b * NCHUNK + c) * SUB;
        const int n = ccnt[c], o = coff[c];
        for (int i = tid & 31; i < n; i += 32) cand[o + i] = cb[i];
    } else {
        // full scan fallback (data-dependent; covers ws-overflow / no-ws)
        for (int q = tid; q < nq; q += NT) {
            float4 v = cp[q];
            #pragma unroll
            for (int h = 0; h < 2; ++h) {
                float s = h ? v.w : v.y;
                if (s >= FAST_T) {
                    int pos = atomicAdd(&cand_count, 1);
                    if (pos < CAND_MAX) {
                        unsigned int m = __float_as_uint(s) ^ 0xFFFFFFFFu;
                        cand[pos] = ((u64)m << 32) | (unsigned int)(2 * q + h);
                    }
                }
            }
        }
        __syncthreads();
        if (cand_count < PRE_NMS) {
            // histogram fallback (hist aliases cand; cand dead here)
            for (int i = tid; i < NBUCKET; i += NT) hist[i] = 0;
            __syncthreads();
            for (int q = tid; q < nq; q += NT) {
                float4 v = cp[q];
                if (v.y >= SCORE_T) atomicAdd(&hist[min((int)(v.y * (float)NBUCKET), NBUCKET - 1)], 1);
                if (v.w >= SCORE_T) atomicAdd(&hist[min((int)(v.w * (float)NBUCKET), NBUCKET - 1)], 1);
            }
            __syncthreads();
            if (tid == 0) {
                int acc = 0, c = 0;
                for (int i = NBUCKET - 1; i >= 0; --i) {
                    acc += hist[i];
                    if (acc >= PRE_NMS) { c = i; break; }
                }
                cutoff = c;
                cand_count = 0;
            }
            __syncthreads();
            const int c = cutoff;
            for (int q = tid; q < nq; q += NT) {
                float4 v = cp[q];
                #pragma unroll
                for (int h = 0; h < 2; ++h) {
                    float s = h ? v.w : v.y;
                    if (s >= SCORE_T) {
                        int bu = min((int)(s * (float)NBUCKET), NBUCKET - 1);
                        if (bu >= c) {
                            int pos = atomicAdd(&cand_count, 1);
                            if (pos < CAND_MAX) {
                                unsigned int m = __float_as_uint(s) ^ 0xFFFFFFFFu;
                                cand[pos] = ((u64)m << 32) | (unsigned int)(2 * q + h);
                            }
                        }
                    }
                }
            }
            __syncthreads();
        }
        cc = min(cand_count, CAND_MAX);
        if (tid == 0) sh_cc = cc;
        __syncthreads();
        cc = sh_cc;
    }

    // zero bb so ranks >= Kv read as degenerate (0,0,0,0) boxes
    for (int k = tid; k < PRE_NMS; k += NT) bb[k] = make_float4(0.f, 0.f, 0.f, 0.f);
    __syncthreads();

    const int Kv = min(cc, PRE_NMS);

    // ---- 2. fused rank-select + decode: global gathers issue before the
    //      rank loop (latency hidden under ~cc LDS broadcast reads), then
    //      scatter decoded float4 straight to bb[rank]. Keys unique. ----
    const float hmax = im_info[b * 3 + 0] - 1.0f;
    const float wmax = im_info[b * 3 + 1] - 1.0f;
    for (int c = tid; c < cc; c += NT) {
        u64 my = cand[c];
        int idx = (int)(my & 0xFFFFFFFFull);
        float4 bo = *(const float4*)(boxes  + ((size_t)b * N + idx) * 4);  // early issue
        float4 de = *(const float4*)(deltas + ((size_t)b * N + idx) * 4);
        int rank = 0;
        for (int k = 0; k < cc; ++k) rank += (cand[k] < my) ? 1 : 0;
        if (rank < PRE_NMS) {
            float w  = bo.z - bo.x + 1.0f;
            float hh = bo.w - bo.y + 1.0f;
            float cx = bo.x + 0.5f * w;
            float cy = bo.y + 0.5f * hh;
            float pcx = de.x * 0.1f * w + cx;
            float pcy = de.y * 0.1f * hh + cy;
            float pw  = expf(de.z * 0.2f) * w;
            float ph  = expf(de.w * 0.2f) * hh;
            float x1 = fminf(fmaxf(pcx - 0.5f * pw, 0.0f), wmax);
            float y1 = fminf(fmaxf(pcy - 0.5f * ph, 0.0f), hmax);
            float x2 = fminf(fmaxf(pcx + 0.5f * pw, 0.0f), wmax);
            float y2 = fminf(fmaxf(pcy + 0.5f * ph, 0.0f), hmax);
            bb[rank] = make_float4(x1, y1, x2, y2);
        }
    }
    __syncthreads();

    // ---- 3. suppression matrix; single float4 read per j, areas in-register;
    //      bits j<=i written 0 so NMS ANDs rows unmasked ----
    for (int t = tid; t < PRE_NMS * NWORDS; t += NT) {
        int w = t / PRE_NMS;
        int i = t - w * PRE_NMS;
        int jbase = w * 64;
        int jend  = min(jbase + 64, PRE_NMS);
        u64 bits = 0;
        int jstart = max(jbase, i + 1);   // bits j<=i stay 0
        if (jstart < jend) {
            float4 bi = bb[i];
            float ai = (bi.z - bi.x + 1.0f) * (bi.w - bi.y + 1.0f);
            for (int j = jstart; j < jend; ++j) {
                float4 bj = bb[j];
                float aj = (bj.z - bj.x + 1.0f) * (bj.w - bj.y + 1.0f);
                float xx1 = fmaxf(bi.x, bj.x);
                float yy1 = fmaxf(bi.y, bj.y);
                float xx2 = fminf(bi.z, bj.z);
                float yy2 = fminf(bi.w, bj.w);
                float iw = fmaxf(xx2 - xx1 + 1.0f, 0.0f);
                float ih = fmaxf(yy2 - yy1 + 1.0f, 0.0f);
                float inter = iw * ih;
                float iou = inter / (ai + aj - inter);
                if (iou > NMS_T) bits |= (1ull << (j - jbase));
            }
        }
        supRow[i * SUP_STRIDE + w] = bits;
    }
    __syncthreads();

    // ---- 4. greedy NMS: wave 0 uniform, ffs-driven alive-skip ----
    if (tid < 64) {
        u64 kw0 = keep_init_word(Kv, 0);
        u64 kw1 = keep_init_word(Kv, 1);
        u64 kw2 = keep_init_word(Kv, 2);
        u64 kw3 = keep_init_word(Kv, 3);
        u64 kw4 = keep_init_word(Kv, 4);

        int nk = 0;
        #pragma unroll
        for (int wi = 0; wi < NWORDS; ++wi) {
            if (nk >= POST_K) break;
            u64 w = (wi == 0) ? kw0 : (wi == 1) ? kw1 : (wi == 2) ? kw2 : (wi == 3) ? kw3 : kw4;
            while (w != 0ull && nk < POST_K) {
                int bit = __ffsll(w) - 1;
                int i = wi * 64 + bit;
                const u64* r = supRow + i * SUP_STRIDE;   // 64B-aligned row
                u64 r0 = r[0], r1 = r[1], r2 = r[2], r3 = r[3], r4 = r[4];
                kw0 &= ~r0; kw1 &= ~r1; kw2 &= ~r2; kw3 &= ~r3; kw4 &= ~r4;
                ++nk;
                u64 self = (wi == 0) ? kw0 : (wi == 1) ? kw1 : (wi == 2) ? kw2 : (wi == 3) ? kw3 : kw4;
                u64 below = (bit == 63) ? ~0ull : ((1ull << (bit + 1)) - 1ull);
                w = self & ~below;        // alive bits strictly above current
            }
        }
        if (tid == 0) {
            keepw[0] = kw0; keepw[1] = kw1; keepw[2] = kw2; keepw[3] = kw3; keepw[4] = kw4;
            n_out = nk;
        }
    }
    __syncthreads();

    // ---- 5. parallel compaction (cap via prefix < POST_K) ----
    if (tid < PRE_NMS) {
        int wi = tid >> 6, bi = tid & 63;
        u64 w = keepw[wi];
        int prefix = 0;
        #pragma unroll
        for (int ww = 0; ww < NWORDS; ++ww)
            if (ww < wi) prefix += __popcll(keepw[ww]);
        prefix += __popcll(w & ((1ull << bi) - 1ull));
        if (((w >> bi) & 1ull) && prefix < POST_K) sel[prefix] = tid;
    }
    __syncthreads();

    // ---- 6. output ----
    if (tid < POST_K) {
        float* op = out + ((size_t)b * POST_K + tid) * 5;
        op[0] = (float)b;
        if (tid < n_out) {
            float4 v = bb[sel[tid]];
            op[1] = v.x; op[2] = v.y; op[3] = v.z; op[4] = v.w;
        } else {
            op[1] = 0.0f; op[2] = 0.0f; op[3] = 0.0f; op[4] = 0.0f;
        }
    }
}

extern "C" void kernel_launch(void* const* d_in, const int* in_sizes, int n_in,
                              void* d_out, int out_size, void* d_ws, size_t ws_size,
                              hipStream_t stream) {
    const float* cls_prob = (const float*)d_in[0];
    const float* boxes    = (const float*)d_in[1];
    const float* deltas   = (const float*)d_in[2];
    const float* im_info  = (const float*)d_in[3];
    float* out = (float*)d_out;

    const int B = in_sizes[3] / 3;
    const int N = in_sizes[0] / (B * 2);

    int* cntG   = (int*)d_ws;                               // B*NCHUNK ints
    u64* candG  = (u64*)((char*)d_ws + 16384);              // B*NCHUNK*SUB u64
    size_t need = 16384 + (size_t)B * NCHUNK * SUB * sizeof(u64);
    int useWS   = (ws_size >= need && B * NCHUNK * (int)sizeof(int) <= 16384) ? 1 : 0;

    if (useWS) {
        scan_kernel<<<B * NCHUNK, 256, 0, stream>>>(cls_prob, candG, cntG, N);
    }
    proposal_kernel<<<B, 512, 0, stream>>>(cls_prob, boxes, deltas, im_info, out,
                                           candG, cntG, useWS, N);
}